// Round 17
// baseline (327.205 us; speedup 1.0000x reference)
//
#include <hip/hip_runtime.h>
#include <hip/hip_bf16.h>
#include <math.h>

#define NB 256
#define NL 50
#define NK 100
#define NHID 64
#define NBL (NB * NL)            // 12800 (b,l) pairs
#define NTILE 7                  // ceil(100/16) M-tiles per (b,l), one per wave

typedef __attribute__((ext_vector_type(8))) short short8;   // 8 bf16 = 4 VGPR
typedef __attribute__((ext_vector_type(4))) float floatx4;  // C/D frag

__device__ __forceinline__ short f2bf(float f) {
    __hip_bfloat16 h = __float2bfloat16(f);
    return *reinterpret_cast<short*>(&h);
}

// ---- init: zero acc ----
__global__ __launch_bounds__(256) void init_kernel(float* __restrict__ acc) {
    int t = blockIdx.x * 256 + threadIdx.x;
    if (t < NB * NHID) acc[t] = 0.f;
}

// ---- pack weights: bf16 fragment order + transposed Wa_top ----
// k-major frag: lane l holds W[k = kstep*32 + (l>>4)*8 + j][n0 + (l&15)], j=0..7
// (valid as either A- or B-operand -- identical per-lane indexing)
__global__ __launch_bounds__(256) void pack_kernel(
    const float* __restrict__ Wa, const float* __restrict__ W1,
    const float* __restrict__ W2,
    short* __restrict__ WaP, short* __restrict__ W1P, short* __restrict__ W2P,
    float* __restrict__ WaTopT)
{
    int t = threadIdx.x;
    for (int s = t; s < 12 * 64; s += 256) {        // Wa_bot [64,96]: 6 ntiles x 2 ksteps
        int l = s & 63, nt = s >> 6, n = nt >> 1, tk = nt & 1;
        int col = n * 16 + (l & 15);
        for (int j = 0; j < 8; ++j) {
            int k = tk * 32 + ((l >> 4) * 8) + j;
            WaP[s * 8 + j] = f2bf(Wa[(64 + k) * 96 + col]);
        }
    }
    for (int s = t; s < 9 * 64; s += 256) {         // W1 [96,48]: 3 ntiles x 3 ksteps
        int l = s & 63, nt = s >> 6, n = nt / 3, tk = nt % 3;
        int col = n * 16 + (l & 15);
        for (int j = 0; j < 8; ++j) {
            int k = tk * 32 + ((l >> 4) * 8) + j;
            W1P[s * 8 + j] = f2bf(W1[k * 48 + col]);
        }
    }
    for (int s = t; s < 2 * 64; s += 256) {         // W2 [48,16] pad K->64
        int l = s & 63, tk = s >> 6;
        int col = l & 15;
        for (int j = 0; j < 8; ++j) {
            int k = tk * 32 + ((l >> 4) * 8) + j;
            W2P[s * 8 + j] = (k < 48) ? f2bf(W2[k * 16 + col]) : (short)0;
        }
    }
    for (int s = t; s < 96 * 64; s += 256) {        // WaTopT[j][i] = Wa[i][j]
        int j = s >> 6, i = s & 63;
        WaTopT[s] = Wa[i * 96 + j];
    }
}

// ---- base1_all[bl][96] = ba + hist(bl) . Wa_top ----
__global__ __launch_bounds__(128) void base1_kernel(
    const int* __restrict__ history,
    const float* __restrict__ item_table,
    const float* __restrict__ ba,
    const float* __restrict__ WaTopT,
    float* __restrict__ base1_all)
{
    const int bl = blockIdx.x, tid = threadIdx.x;
    __shared__ float hist_s[64];
    const int hid = history[bl];
    if (tid < 64) hist_s[tid] = item_table[(size_t)hid * NHID + tid];
    __syncthreads();
    if (tid < 96) {
        float a = ba[tid];
        const float4* wr = reinterpret_cast<const float4*>(WaTopT + tid * 64);
        #pragma unroll
        for (int i4 = 0; i4 < 16; ++i4) {
            float4 w = wr[i4];
            a += hist_s[i4 * 4 + 0] * w.x + hist_s[i4 * 4 + 1] * w.y
               + hist_s[i4 * 4 + 2] * w.z + hist_s[i4 * 4 + 3] * w.w;
        }
        base1_all[bl * 96 + tid] = a;
    }
}

// ---- fused edge kernel: one block per (b,l), 7 waves = 7 M-tiles ----
// SWAPPED MFMA: compute z^T = mfma(W_frag, x_frag) so activations stay in
// registers (lane = edge). Layer-to-layer k-regroup via __shfl gather
// (src lane ((lg&1)*2+(j>>2))*16+lr, tile 2ks+(lg>>1)). No z-LDS at all.
__global__ __launch_bounds__(448) void edge_kernel(
    const float* __restrict__ neighbor,
    const float* __restrict__ base1_all,
    const float* __restrict__ b1v, const float* __restrict__ b2,
    const float* __restrict__ W3, const float* __restrict__ b3,
    const short* __restrict__ WaP, const short* __restrict__ W1P,
    const short* __restrict__ W2P,
    const float* __restrict__ Wh, const float* __restrict__ bh,
    float* __restrict__ acc_out)
{
    const int bl  = blockIdx.x;
    const int tid = threadIdx.x;
    const int wv  = tid >> 6;        // 0..6 = M-tile
    const int ln  = tid & 63;
    const int lr  = ln & 15;         // edge within tile (C-col after swap)
    const int lg  = ln >> 4;

    __shared__ float logit_s[112];
    __shared__ float w_s[128];
    __shared__ float part_s[NTILE][64];
    __shared__ float agg_s[64];

    const float* nbg = neighbor + (size_t)bl * (NK * NHID);
    const int k  = wv * 16 + lr;
    const int kc = (k > NK - 1) ? NK - 1 : k;        // clamp; junk masked at softmax

    // nb fragment (B-operand after swap; same per-lane data as proven R11 path)
    const float* arow = nbg + kc * NHID + lg * 8;
    float4 f0 = *reinterpret_cast<const float4*>(arow);
    float4 f1 = *reinterpret_cast<const float4*>(arow + 4);
    float4 f2 = *reinterpret_cast<const float4*>(arow + 32);
    float4 f3 = *reinterpret_cast<const float4*>(arow + 36);
    short8 a0, a1;
    a0[0] = f2bf(f0.x); a0[1] = f2bf(f0.y); a0[2] = f2bf(f0.z); a0[3] = f2bf(f0.w);
    a0[4] = f2bf(f1.x); a0[5] = f2bf(f1.y); a0[6] = f2bf(f1.z); a0[7] = f2bf(f1.w);
    a1[0] = f2bf(f2.x); a1[1] = f2bf(f2.y); a1[2] = f2bf(f2.z); a1[3] = f2bf(f2.w);
    a1[4] = f2bf(f3.x); a1[5] = f2bf(f3.y); a1[6] = f2bf(f3.z); a1[7] = f2bf(f3.w);

    const short8* WaPv = reinterpret_cast<const short8*>(WaP);
    const short8* W1Pv = reinterpret_cast<const short8*>(W1P);
    const short8* W2Pv = reinterpret_cast<const short8*>(W2P);
    const float b3s = b3[0];
    const float* base1 = base1_all + bl * 96;

    // shuffle-gather constants
    const int srcA = ((ln >> 4) & 1) * 32 + lr;      // group 2*(lg&1)
    const int srcB = srcA + 16;                      // group 2*(lg&1)+1
    const bool hi  = (ln >= 32);                     // tile select lg>=2

    // ---- L1 swapped: c1[t] = z1^T tile t; lane holds z1[edge=lr][t*16+lg*4+i] ----
    floatx4 c1[6];
    #pragma unroll
    for (int t = 0; t < 6; ++t) {
        floatx4 acc = {0.f, 0.f, 0.f, 0.f};
        acc = __builtin_amdgcn_mfma_f32_16x16x32_bf16(WaPv[(t * 2 + 0) * 64 + ln], a0, acc, 0, 0, 0);
        acc = __builtin_amdgcn_mfma_f32_16x16x32_bf16(WaPv[(t * 2 + 1) * 64 + ln], a1, acc, 0, 0, 0);
        floatx4 bb = *reinterpret_cast<const floatx4*>(base1 + t * 16 + lg * 4);
        #pragma unroll
        for (int i = 0; i < 4; ++i) c1[t][i] = fmaxf(acc[i] + bb[i], 0.f);
    }

    // ---- L2 swapped: regroup z1 into B-frags via shfl; c2[t] = z2^T ----
    floatx4 c2[3] = {{0.f,0.f,0.f,0.f},{0.f,0.f,0.f,0.f},{0.f,0.f,0.f,0.f}};
    #pragma unroll
    for (int ks = 0; ks < 3; ++ks) {
        short8 bf;
        #pragma unroll
        for (int i = 0; i < 4; ++i) {
            float va = __shfl(c1[2 * ks][i],     srcA, 64);
            float vb = __shfl(c1[2 * ks + 1][i], srcA, 64);
            bf[i] = f2bf(hi ? vb : va);
            float vc = __shfl(c1[2 * ks][i],     srcB, 64);
            float vd = __shfl(c1[2 * ks + 1][i], srcB, 64);
            bf[4 + i] = f2bf(hi ? vd : vc);
        }
        #pragma unroll
        for (int t = 0; t < 3; ++t)
            c2[t] = __builtin_amdgcn_mfma_f32_16x16x32_bf16(W1Pv[(t * 3 + ks) * 64 + ln], bf, c2[t], 0, 0, 0);
    }
    #pragma unroll
    for (int t = 0; t < 3; ++t) {
        floatx4 bb = *reinterpret_cast<const floatx4*>(b1v + t * 16 + lg * 4);
        #pragma unroll
        for (int i = 0; i < 4; ++i) c2[t][i] = fmaxf(c2[t][i] + bb[i], 0.f);
    }

    // ---- L3 swapped: K=48 (ks=1 upper half zero); c3 = z3^T ----
    floatx4 c3 = {0.f, 0.f, 0.f, 0.f};
    {
        short8 bf;
        #pragma unroll
        for (int i = 0; i < 4; ++i) {               // ks=0: tiles 0,1
            float va = __shfl(c2[0][i], srcA, 64);
            float vb = __shfl(c2[1][i], srcA, 64);
            bf[i] = f2bf(hi ? vb : va);
            float vc = __shfl(c2[0][i], srcB, 64);
            float vd = __shfl(c2[1][i], srcB, 64);
            bf[4 + i] = f2bf(hi ? vd : vc);
        }
        c3 = __builtin_amdgcn_mfma_f32_16x16x32_bf16(W2Pv[ln], bf, c3, 0, 0, 0);
        #pragma unroll
        for (int i = 0; i < 4; ++i) {               // ks=1: tile 2, k>=48 zero
            float va = __shfl(c2[2][i], srcA, 64);
            bf[i] = hi ? (short)0 : f2bf(va);
            float vc = __shfl(c2[2][i], srcB, 64);
            bf[4 + i] = hi ? (short)0 : f2bf(vc);
        }
        c3 = __builtin_amdgcn_mfma_f32_16x16x32_bf16(W2Pv[64 + ln], bf, c3, 0, 0, 0);
    }

    // ---- logit: lane holds z3[edge=lr][n=lg*4+i]; reduce over n via 2 shfl_xor ----
    {
        floatx4 b2v = *reinterpret_cast<const floatx4*>(b2 + lg * 4);
        floatx4 w3v = *reinterpret_cast<const floatx4*>(W3 + lg * 4);
        float p = 0.f;
        #pragma unroll
        for (int i = 0; i < 4; ++i)
            p += fmaxf(c3[i] + b2v[i], 0.f) * w3v[i];
        p += __shfl_xor(p, 16, 64);
        p += __shfl_xor(p, 32, 64);
        if (lg == 0) logit_s[wv * 16 + lr] = p + b3s;
    }
    __syncthreads();

    // ---- softmax over 100 logits: wave 0 (proven path) ----
    if (wv == 0) {
        float l0 = logit_s[ln];
        float l1 = (ln < NK - 64) ? logit_s[64 + ln] : -1e30f;
        float m = fmaxf(l0, l1);
        #pragma unroll
        for (int off = 32; off > 0; off >>= 1) m = fmaxf(m, __shfl_xor(m, off, 64));
        float p0 = __expf(l0 - m);
        float p1 = (ln < NK - 64) ? __expf(l1 - m) : 0.f;
        float s = p0 + p1;
        #pragma unroll
        for (int off = 32; off > 0; off >>= 1) s += __shfl_xor(s, off, 64);
        float inv = 1.f / s;
        w_s[ln]      = p0 * inv;
        w_s[64 + ln] = (ln < NK - 64) ? p1 * inv : 0.f;
    }
    __syncthreads();

    // ---- agg: 7-way K-split; nbg lines L2-hot (just read above) ----
    {
        float a = 0.f;
        int k0 = wv * 15, k1 = k0 + 15 > NK ? NK : k0 + 15;   // 15,...,15,10
        for (int kk = k0; kk < k1; ++kk)
            a += w_s[kk] * nbg[kk * NHID + ln];
        part_s[wv][ln] = a;
    }
    __syncthreads();

    // ---- heads + accumulate: wave 0 ----
    if (wv == 0) {
        float ag = part_s[0][ln] + part_s[1][ln] + part_s[2][ln] + part_s[3][ln]
                 + part_s[4][ln] + part_s[5][ln] + part_s[6][ln];
        agg_s[ln] = ag;
        const int n = ln >> 4, d = ln & 15;
        float hv = bh[ln];
        #pragma unroll 4
        for (int h = 0; h < 64; ++h)
            hv += agg_s[h] * Wh[n * (64 * 16) + h * 16 + d];
        atomicAdd(&acc_out[(bl / NL) * NHID + ln], hv);
    }
}

// ---- final head ----
__global__ __launch_bounds__(64) void final_kernel(
    const int* __restrict__ user_ids,
    const float* __restrict__ user_table,
    const float* __restrict__ acc,
    const float* __restrict__ Wf1, const float* __restrict__ bf1,
    const float* __restrict__ Wo,  const float* __restrict__ bo,
    float* __restrict__ out)
{
    const int b = blockIdx.x, h = threadIdx.x;
    __shared__ float ue[64], ag[64];
    const int uid = user_ids[b];
    ue[h] = user_table[(size_t)uid * 64 + h];
    ag[h] = acc[b * 64 + h] * (1.f / 50.f);
    __syncthreads();
    float z = bf1[h];
    #pragma unroll 4
    for (int i = 0; i < 64; ++i) z += ue[i] * Wf1[i * 64 + h];
    #pragma unroll 4
    for (int i = 0; i < 64; ++i) z += ag[i] * Wf1[(64 + i) * 64 + h];
    float t = fmaxf(z, 0.f) * Wo[h];
    #pragma unroll
    for (int off = 32; off > 0; off >>= 1) t += __shfl_down(t, off, 64);
    if (h == 0) out[b] = 1.f / (1.f + __expf(-(t + bo[0])));
}

extern "C" void kernel_launch(void* const* d_in, const int* in_sizes, int n_in,
                              void* d_out, int out_size, void* d_ws, size_t ws_size,
                              hipStream_t stream) {
    const int*   user_ids   = (const int*)d_in[0];
    const int*   history    = (const int*)d_in[2];
    const float* neighbor   = (const float*)d_in[3];
    const float* user_table = (const float*)d_in[4];
    const float* item_table = (const float*)d_in[5];
    const float* Wa  = (const float*)d_in[6];
    const float* ba  = (const float*)d_in[7];
    const float* W1  = (const float*)d_in[8];
    const float* b1  = (const float*)d_in[9];
    const float* W2  = (const float*)d_in[10];
    const float* b2  = (const float*)d_in[11];
    const float* W3  = (const float*)d_in[12];
    const float* b3  = (const float*)d_in[13];
    const float* Wh  = (const float*)d_in[14];
    const float* bh  = (const float*)d_in[15];
    const float* Wf1 = (const float*)d_in[16];
    const float* bf1 = (const float*)d_in[17];
    const float* Wo  = (const float*)d_in[18];
    const float* bo  = (const float*)d_in[19];

    char* ws = (char*)d_ws;
    float* acc       = (float*)(ws);                         // 65536 B
    short* WaP       = (short*)(ws + 65536);                 // 12288 B
    short* W1P       = (short*)(ws + 77824);                 // 9216 B
    short* W2P       = (short*)(ws + 87040);                 // 2048 B
    float* WaTopT    = (float*)(ws + 89088);                 // 24576 B
    float* base1_all = (float*)(ws + 113664);                // 4915200 B -> 5028864 total

    init_kernel<<<(NB * NHID + 255) / 256, 256, 0, stream>>>(acc);
    pack_kernel<<<1, 256, 0, stream>>>(Wa, W1, W2, WaP, W1P, W2P, WaTopT);
    base1_kernel<<<NBL, 128, 0, stream>>>(history, item_table, ba, WaTopT, base1_all);
    edge_kernel<<<NBL, 448, 0, stream>>>(neighbor, base1_all,
        b1, b2, W3, b3, WaP, W1P, W2P, Wh, bh, acc);
    final_kernel<<<NB, 64, 0, stream>>>(user_ids, user_table, acc, Wf1, bf1, Wo, bo,
                                        (float*)d_out);
}

// Round 18
// 254.457 us; speedup vs baseline: 1.2859x; 1.2859x over previous
//
#include <hip/hip_runtime.h>
#include <hip/hip_bf16.h>
#include <math.h>

#define NB 256
#define NL 50
#define NK 100
#define NHID 64
#define NBL (NB * NL)            // 12800 (b,l) pairs

typedef __attribute__((ext_vector_type(8))) short short8;   // 8 bf16 = 4 VGPR
typedef __attribute__((ext_vector_type(4))) float floatx4;  // C/D frag

__device__ __forceinline__ short f2bf(float f) {
    __hip_bfloat16 h = __float2bfloat16(f);
    return *reinterpret_cast<short*>(&h);
}

// ---- init: zero acc ----
__global__ __launch_bounds__(256) void init_kernel(float* __restrict__ acc) {
    int t = blockIdx.x * 256 + threadIdx.x;
    if (t < NB * NHID) acc[t] = 0.f;
}

// ---- pack weights: bf16 B-fragment order + transposed Wa_top ----
// B-frag for 16x16x32: lane l holds B[k = kstep*32 + (l>>4)*8 + j][n0 + (l&15)], j=0..7
__global__ __launch_bounds__(256) void pack_kernel(
    const float* __restrict__ Wa, const float* __restrict__ W1,
    const float* __restrict__ W2,
    short* __restrict__ WaP, short* __restrict__ W1P, short* __restrict__ W2P,
    float* __restrict__ WaTopT)
{
    int t = threadIdx.x;
    for (int s = t; s < 12 * 64; s += 256) {        // Wa_bot [64,96]: 6 ntiles x 2 ksteps
        int l = s & 63, nt = s >> 6, n = nt >> 1, tk = nt & 1;
        int col = n * 16 + (l & 15);
        for (int j = 0; j < 8; ++j) {
            int k = tk * 32 + ((l >> 4) * 8) + j;
            WaP[s * 8 + j] = f2bf(Wa[(64 + k) * 96 + col]);
        }
    }
    for (int s = t; s < 9 * 64; s += 256) {         // W1 [96,48]: 3 ntiles x 3 ksteps
        int l = s & 63, nt = s >> 6, n = nt / 3, tk = nt % 3;
        int col = n * 16 + (l & 15);
        for (int j = 0; j < 8; ++j) {
            int k = tk * 32 + ((l >> 4) * 8) + j;
            W1P[s * 8 + j] = f2bf(W1[k * 48 + col]);
        }
    }
    for (int s = t; s < 2 * 64; s += 256) {         // W2 [48,16] pad K->64
        int l = s & 63, tk = s >> 6;
        int col = l & 15;
        for (int j = 0; j < 8; ++j) {
            int k = tk * 32 + ((l >> 4) * 8) + j;
            W2P[s * 8 + j] = (k < 48) ? f2bf(W2[k * 16 + col]) : (short)0;
        }
    }
    for (int s = t; s < 96 * 64; s += 256) {        // WaTopT[j][i] = Wa[i][j]
        int j = s >> 6, i = s & 63;
        WaTopT[s] = Wa[i * 96 + j];
    }
}

// ---- base1_all[bl][96] = ba + hist(bl) . Wa_top ----
__global__ __launch_bounds__(128) void base1_kernel(
    const int* __restrict__ history,
    const float* __restrict__ item_table,
    const float* __restrict__ ba,
    const float* __restrict__ WaTopT,
    float* __restrict__ base1_all)
{
    const int bl = blockIdx.x, tid = threadIdx.x;
    __shared__ float hist_s[64];
    const int hid = history[bl];
    if (tid < 64) hist_s[tid] = item_table[(size_t)hid * NHID + tid];
    __syncthreads();
    if (tid < 96) {
        float a = ba[tid];
        const float4* wr = reinterpret_cast<const float4*>(WaTopT + tid * 64);
        #pragma unroll
        for (int i4 = 0; i4 < 16; ++i4) {
            float4 w = wr[i4];
            a += hist_s[i4 * 4 + 0] * w.x + hist_s[i4 * 4 + 1] * w.y
               + hist_s[i4 * 4 + 2] * w.z + hist_s[i4 * 4 + 3] * w.w;
        }
        base1_all[bl * 96 + tid] = a;
    }
}

// ---- fused edge kernel: one block per (b,l), 4 waves x 2 M-tiles ----
// R16's proven MLP body; ONE barrier; per-wave redundant softmax; partial agg
// with direct atomicAdd; heads hoisted out via linearity (mean∘heads = heads∘mean).
__global__ __launch_bounds__(256) void edge_kernel(
    const float* __restrict__ neighbor,
    const float* __restrict__ base1_all,
    const float* __restrict__ b1v, const float* __restrict__ b2,
    const float* __restrict__ W3, const float* __restrict__ b3,
    const short* __restrict__ WaP, const short* __restrict__ W1P,
    const short* __restrict__ W2P,
    float* __restrict__ acc_out)
{
    const int bl  = blockIdx.x;
    const int tid = threadIdx.x;
    const int wv  = tid >> 6;        // 0..3
    const int ln  = tid & 63;
    const int lr  = ln & 15;         // A-row / C-col within tile
    const int lg  = ln >> 4;         // k-group / C-row-group

    __shared__ __align__(16) char z12_s[4][3072]; // per-wave z1[16]x192B / z2[16]x128B
    __shared__ float logit_s[112];
    char* zp = z12_s[wv];

    const float* nbg = neighbor + (size_t)bl * (NK * NHID);

    const short8* WaPv = reinterpret_cast<const short8*>(WaP);
    const short8* W1Pv = reinterpret_cast<const short8*>(W1P);
    const short8* W2Pv = reinterpret_cast<const short8*>(W2P);
    const float b2c = b2[lr], w3c = W3[lr], b3s = b3[0];
    const int lsw = (lr & 7) << 4;
    const float* base1 = base1_all + bl * 96;

    // ---- prefetch A-frag source rows for BOTH tiles early (latency overlap) ----
    const int er0 = wv * 16 + lr;                        // tile mi0 = wv (always < 100)
    const int mi1 = wv + 4;                              // tile mi1 (wv<3 only)
    const int er1 = mi1 * 16 + lr;
    const int ec1 = (er1 > NK - 1) ? NK - 1 : er1;       // clamp junk rows
    const float* arow0 = nbg + er0 * NHID + lg * 8;
    const float* arow1 = nbg + ec1 * NHID + lg * 8;
    float4 g0 = *reinterpret_cast<const float4*>(arow0);
    float4 g1 = *reinterpret_cast<const float4*>(arow0 + 4);
    float4 g2 = *reinterpret_cast<const float4*>(arow0 + 32);
    float4 g3 = *reinterpret_cast<const float4*>(arow0 + 36);
    float4 h0, h1, h2, h3;
    if (mi1 < 7) {
        h0 = *reinterpret_cast<const float4*>(arow1);
        h1 = *reinterpret_cast<const float4*>(arow1 + 4);
        h2 = *reinterpret_cast<const float4*>(arow1 + 32);
        h3 = *reinterpret_cast<const float4*>(arow1 + 36);
    }

    // ---- MLP for a tile (R16 body) ----
    auto mlp_tile = [&](int mi, float4 f0, float4 f1, float4 f2, float4 f3) {
        short8 a0, a1;
        a0[0] = f2bf(f0.x); a0[1] = f2bf(f0.y); a0[2] = f2bf(f0.z); a0[3] = f2bf(f0.w);
        a0[4] = f2bf(f1.x); a0[5] = f2bf(f1.y); a0[6] = f2bf(f1.z); a0[7] = f2bf(f1.w);
        a1[0] = f2bf(f2.x); a1[1] = f2bf(f2.y); a1[2] = f2bf(f2.z); a1[3] = f2bf(f2.w);
        a1[4] = f2bf(f3.x); a1[5] = f2bf(f3.y); a1[6] = f2bf(f3.z); a1[7] = f2bf(f3.w);

        // L1: [16,64] x [64,96] -> relu(+base1) -> z1 (LDS, 192B rows)
        #pragma unroll
        for (int n = 0; n < 6; ++n) {
            floatx4 acc = {0.f, 0.f, 0.f, 0.f};
            acc = __builtin_amdgcn_mfma_f32_16x16x32_bf16(a0, WaPv[(n * 2 + 0) * 64 + ln], acc, 0, 0, 0);
            acc = __builtin_amdgcn_mfma_f32_16x16x32_bf16(a1, WaPv[(n * 2 + 1) * 64 + ln], acc, 0, 0, 0);
            float base = base1[n * 16 + lr];
            #pragma unroll
            for (int i = 0; i < 4; ++i) {
                int r = lg * 4 + i;
                float z = fmaxf(acc[i] + base, 0.f);
                *reinterpret_cast<short*>(zp + r * 192 + ((2 * (n * 16 + lr)) ^ ((r & 7) << 4))) = f2bf(z);
            }
        }

        // L2: [16,96] x [96,48] -> relu(+b1) -> z2 (overlays z1; z1 in regs first)
        short8 za0 = *reinterpret_cast<const short8*>(zp + lr * 192 + ((  0 + lg * 16) ^ lsw));
        short8 za1 = *reinterpret_cast<const short8*>(zp + lr * 192 + (( 64 + lg * 16) ^ lsw));
        short8 za2 = *reinterpret_cast<const short8*>(zp + lr * 192 + ((128 + lg * 16) ^ lsw));
        #pragma unroll
        for (int n = 0; n < 3; ++n) {
            floatx4 acc = {0.f, 0.f, 0.f, 0.f};
            acc = __builtin_amdgcn_mfma_f32_16x16x32_bf16(za0, W1Pv[(n * 3 + 0) * 64 + ln], acc, 0, 0, 0);
            acc = __builtin_amdgcn_mfma_f32_16x16x32_bf16(za1, W1Pv[(n * 3 + 1) * 64 + ln], acc, 0, 0, 0);
            acc = __builtin_amdgcn_mfma_f32_16x16x32_bf16(za2, W1Pv[(n * 3 + 2) * 64 + ln], acc, 0, 0, 0);
            float bias = b1v[n * 16 + lr];
            #pragma unroll
            for (int i = 0; i < 4; ++i) {
                int r = lg * 4 + i;
                float z = fmaxf(acc[i] + bias, 0.f);
                *reinterpret_cast<short*>(zp + r * 128 + ((2 * (n * 16 + lr)) ^ ((r & 7) << 4))) = f2bf(z);
            }
        }

        // L3: [16,48] x [48,16(pad64)] -> relu(+b2) . W3 -> logits (LDS)
        short8 zb0 = *reinterpret_cast<const short8*>(zp + lr * 128 + ((lg * 16) ^ lsw));
        short8 zb1 = short8{0, 0, 0, 0, 0, 0, 0, 0};
        if (lg < 2)
            zb1 = *reinterpret_cast<const short8*>(zp + lr * 128 + ((64 + lg * 16) ^ lsw));
        floatx4 acc3 = {0.f, 0.f, 0.f, 0.f};
        acc3 = __builtin_amdgcn_mfma_f32_16x16x32_bf16(zb0, W2Pv[ln], acc3, 0, 0, 0);
        acc3 = __builtin_amdgcn_mfma_f32_16x16x32_bf16(zb1, W2Pv[64 + ln], acc3, 0, 0, 0);
        #pragma unroll
        for (int i = 0; i < 4; ++i) {
            float tL = fmaxf(acc3[i] + b2c, 0.f) * w3c;
            tL += __shfl_xor(tL, 1, 64);
            tL += __shfl_xor(tL, 2, 64);
            tL += __shfl_xor(tL, 4, 64);
            tL += __shfl_xor(tL, 8, 64);
            int krow = mi * 16 + lg * 4 + i;
            if (lr == 0 && krow < NK) logit_s[krow] = tL + b3s;
        }
    };

    mlp_tile(wv, g0, g1, g2, g3);
    if (mi1 < 7) mlp_tile(mi1, h0, h1, h2, h3);
    __syncthreads();                                  // the ONLY barrier

    // ---- softmax (redundant per wave, in-register) ----
    float l0 = logit_s[ln];
    float l1 = (ln < NK - 64) ? logit_s[64 + ln] : -1e30f;
    float m = fmaxf(l0, l1);
    #pragma unroll
    for (int off = 32; off > 0; off >>= 1) m = fmaxf(m, __shfl_xor(m, off, 64));
    float p0 = __expf(l0 - m);
    float p1 = (ln < NK - 64) ? __expf(l1 - m) : 0.f;
    float s = p0 + p1;
    #pragma unroll
    for (int off = 32; off > 0; off >>= 1) s += __shfl_xor(s, off, 64);
    float inv = 1.f / s;
    float w0 = p0 * inv;                              // weight for edge ln
    float w1 = p1 * inv;                              // weight for edge 64+ln (ln<36)

    // ---- partial agg over this wave's 25 edges; weights via shfl broadcast ----
    float a = 0.f;
    #pragma unroll
    for (int kk = 0; kk < 25; ++kk) {
        int k = wv * 25 + kk;
        float wk = __shfl((k < 64) ? w0 : w1, k & 63, 64);
        a += wk * nbg[k * NHID + ln];
    }
    atomicAdd(&acc_out[(bl / NL) * NHID + ln], a);
}

// ---- final head: heads(mean agg) + user emb -> Wf1 -> Wo -> sigmoid ----
__global__ __launch_bounds__(64) void final_kernel(
    const int* __restrict__ user_ids,
    const float* __restrict__ user_table,
    const float* __restrict__ acc,
    const float* __restrict__ Wh, const float* __restrict__ bh,
    const float* __restrict__ Wf1, const float* __restrict__ bf1,
    const float* __restrict__ Wo,  const float* __restrict__ bo,
    float* __restrict__ out)
{
    const int b = blockIdx.x, h = threadIdx.x;
    __shared__ float ue[64], agm[64], agh[64];
    const int uid = user_ids[b];
    ue[h]  = user_table[(size_t)uid * 64 + h];
    agm[h] = acc[b * 64 + h] * (1.f / 50.f);          // mean over L
    __syncthreads();
    // heads once per b (linearity: mean∘heads = heads∘mean)
    {
        const int n = h >> 4, d = h & 15;
        float hv = bh[h];
        #pragma unroll 4
        for (int i = 0; i < 64; ++i)
            hv += agm[i] * Wh[n * (64 * 16) + i * 16 + d];
        agh[h] = hv;
    }
    __syncthreads();
    float z = bf1[h];
    #pragma unroll 4
    for (int i = 0; i < 64; ++i) z += ue[i] * Wf1[i * 64 + h];
    #pragma unroll 4
    for (int i = 0; i < 64; ++i) z += agh[i] * Wf1[(64 + i) * 64 + h];
    float t = fmaxf(z, 0.f) * Wo[h];
    #pragma unroll
    for (int off = 32; off > 0; off >>= 1) t += __shfl_down(t, off, 64);
    if (h == 0) out[b] = 1.f / (1.f + __expf(-(t + bo[0])));
}

extern "C" void kernel_launch(void* const* d_in, const int* in_sizes, int n_in,
                              void* d_out, int out_size, void* d_ws, size_t ws_size,
                              hipStream_t stream) {
    const int*   user_ids   = (const int*)d_in[0];
    const int*   history    = (const int*)d_in[2];
    const float* neighbor   = (const float*)d_in[3];
    const float* user_table = (const float*)d_in[4];
    const float* item_table = (const float*)d_in[5];
    const float* Wa  = (const float*)d_in[6];
    const float* ba  = (const float*)d_in[7];
    const float* W1  = (const float*)d_in[8];
    const float* b1  = (const float*)d_in[9];
    const float* W2  = (const float*)d_in[10];
    const float* b2  = (const float*)d_in[11];
    const float* W3  = (const float*)d_in[12];
    const float* b3  = (const float*)d_in[13];
    const float* Wh  = (const float*)d_in[14];
    const float* bh  = (const float*)d_in[15];
    const float* Wf1 = (const float*)d_in[16];
    const float* bf1 = (const float*)d_in[17];
    const float* Wo  = (const float*)d_in[18];
    const float* bo  = (const float*)d_in[19];

    char* ws = (char*)d_ws;
    float* acc       = (float*)(ws);                         // 65536 B
    short* WaP       = (short*)(ws + 65536);                 // 12288 B
    short* W1P       = (short*)(ws + 77824);                 // 9216 B
    short* W2P       = (short*)(ws + 87040);                 // 2048 B
    float* WaTopT    = (float*)(ws + 89088);                 // 24576 B
    float* base1_all = (float*)(ws + 113664);                // 4915200 B -> 5028864 total

    init_kernel<<<(NB * NHID + 255) / 256, 256, 0, stream>>>(acc);
    pack_kernel<<<1, 256, 0, stream>>>(Wa, W1, W2, WaP, W1P, W2P, WaTopT);
    base1_kernel<<<NBL, 128, 0, stream>>>(history, item_table, ba, WaTopT, base1_all);
    edge_kernel<<<NBL, 256, 0, stream>>>(neighbor, base1_all,
        b1, b2, W3, b3, WaP, W1P, W2P, acc);
    final_kernel<<<NB, 64, 0, stream>>>(user_ids, user_table, acc, Wh, bh,
                                        Wf1, bf1, Wo, bo, (float*)d_out);
}